// Round 1
// 292.381 us; speedup vs baseline: 1.0642x; 1.0642x over previous
//
#include <hip/hip_runtime.h>
#include <hip/hip_bf16.h>
#include <math.h>

#define LOG2E_F 1.4426950408889634f

static constexpr int BT = 64;
static constexpr int DK = 64;
static constexpr int DV = 64;
static constexpr float SCALE = 0.125f;
static constexpr int PAD = 72;   // ushort row stride: 144 B, 16B-aligned

typedef unsigned short ushort_t;
typedef __attribute__((ext_vector_type(8))) short short8;
typedef __attribute__((ext_vector_type(4))) float f32x4;
typedef __attribute__((ext_vector_type(4))) ushort_t ushort4v;

#define MFMA16(a, b, c) __builtin_amdgcn_mfma_f32_16x16x32_bf16((a), (b), (c), 0, 0, 0)

// [64][PAD] ushort slab indexers.
// SWZ: XOR-swizzle minor index (bits 3,4) keyed on major index — kills the
// 8-16-way bank conflicts of transposed scalar writes while keeping b128
// fragment reads (8 contiguous minor elems from an 8-aligned base) contiguous.
__device__ __forceinline__ int SWZ(int a, int b){ return a * PAD + (b ^ (((a >> 3) & 3) << 3)); }
// Z slab: swizzle column keyed on row bits 2,3 (write lanes vary col within quads)
__device__ __forceinline__ int ZSW(int r, int c){ return r * PAD + (c ^ (((r >> 2) & 3) << 3)); }
__device__ __forceinline__ int LIN(int r, int c){ return r * PAD + c; }

__device__ __forceinline__ float logsig_log2e(float x){
    float l = (x >= 0.f) ? (-log1pf(expf(-x))) : (x - log1pf(expf(x)));
    return l * LOG2E_F;
}
__device__ __forceinline__ ushort_t f2bf(float x){   // RNE f32 -> bf16 bits
    unsigned u = __builtin_bit_cast(unsigned, x);
    unsigned r = u + 0x7FFFu + ((u >> 16) & 1u);
    return (ushort_t)(r >> 16);
}
__device__ __forceinline__ float bf2f(ushort_t u){
    return __builtin_bit_cast(float, ((unsigned)u) << 16);
}
__device__ __forceinline__ void split_bf(float x, ushort_t& h, ushort_t& l){
    h = f2bf(x);
    l = f2bf(x - bf2f(h));
}

// ===================== Stage A: per-chunk local state (split-bf16 MFMA) ==========
__global__ __launch_bounds__(256, 4) void stageA_kernel(
    const float* __restrict__ kg, const float* __restrict__ vg,
    const float* __restrict__ ig, const float* __restrict__ fg,
    float* __restrict__ A_ws, float* __restrict__ nloc_ws,
    float* __restrict__ fl_ws, float* __restrict__ mloc_ws,
    int T, int NT)
{
    const int ct = blockIdx.x, s = blockIdx.y, tid = threadIdx.x;
    const int w = tid >> 6, lane = tid & 63, ln = lane & 15, quad = lane >> 4;
    const int q8 = quad * 8;

    __shared__ __align__(16) ushort_t kth[BT * PAD];  // kdec^T hi  [kdim][row] swz
    __shared__ __align__(16) ushort_t ktl[BT * PAD];  // kdec^T lo
    __shared__ __align__(16) ushort_t vth[BT * PAD];  // v^T hi     [vdim][row] swz
    __shared__ __align__(16) ushort_t vtl[BT * PAD];  // v^T lo
    __shared__ float gsc[BT];

    const size_t rowbase = (size_t)s * T + (size_t)ct * BT;
    const float* kc = kg + rowbase * DK;
    const float* vc = vg + rowbase * DV;

    float4 kr[4], vr[4];
    #pragma unroll
    for (int i = 0; i < 4; ++i){
        int idx = i * 1024 + tid * 4;
        kr[i] = *(const float4*)(kc + idx);
        vr[i] = *(const float4*)(vc + idx);
    }
    if (tid < 64){
        float b = logsig_log2e(fg[rowbase + tid]);
        #pragma unroll
        for (int off = 1; off < 64; off <<= 1){
            float y = __shfl_up(b, off);
            if (tid >= off) b += y;
        }
        float f_last = __shfl(b, 63);
        float a = ig[rowbase + tid] * LOG2E_F - b;
        float p = a;
        #pragma unroll
        for (int off = 32; off > 0; off >>= 1) p = fmaxf(p, __shfl_xor(p, off));
        gsc[tid] = exp2f(a - p);
        if (tid == 0){ fl_ws[s * NT + ct] = f_last; mloc_ws[s * NT + ct] = f_last + p; }
    }
    __syncthreads();
    // transpose-stage split-bf16 (k scaled by gsc[row]); swizzled scatter (~2-way)
    #pragma unroll
    for (int i = 0; i < 4; ++i){
        int idx = i * 1024 + tid * 4;
        int r = idx >> 6, c0 = idx & 63;
        float g = gsc[r];
        float kv[4] = {kr[i].x * g, kr[i].y * g, kr[i].z * g, kr[i].w * g};
        float vv[4] = {vr[i].x, vr[i].y, vr[i].z, vr[i].w};
        #pragma unroll
        for (int j = 0; j < 4; ++j){
            ushort_t h, l;
            split_bf(kv[j], h, l); kth[SWZ(c0 + j, r)] = h; ktl[SWZ(c0 + j, r)] = l;
            split_bf(vv[j], h, l); vth[SWZ(c0 + j, r)] = h; vtl[SWZ(c0 + j, r)] = l;
        }
    }
    __syncthreads();

    const int m = 16 * w + ln;
    short8 ah0 = *(const short8*)&kth[SWZ(m, q8)];
    short8 ah1 = *(const short8*)&kth[SWZ(m, 32 + q8)];
    short8 al0 = *(const short8*)&ktl[SWZ(m, q8)];
    short8 al1 = *(const short8*)&ktl[SWZ(m, 32 + q8)];
    float* Ab = A_ws + (size_t)(s * NT + ct) * 4096;
    #pragma unroll
    for (int t = 0; t < 4; ++t){
        f32x4 acc = {0.f, 0.f, 0.f, 0.f};
        short8 bh0 = *(const short8*)&vth[SWZ(16 * t + ln, q8)];
        short8 bh1 = *(const short8*)&vth[SWZ(16 * t + ln, 32 + q8)];
        short8 bl0 = *(const short8*)&vtl[SWZ(16 * t + ln, q8)];
        short8 bl1 = *(const short8*)&vtl[SWZ(16 * t + ln, 32 + q8)];
        acc = MFMA16(ah0, bh0, acc);
        acc = MFMA16(ah1, bh1, acc);
        acc = MFMA16(ah0, bl0, acc);
        acc = MFMA16(ah1, bl1, acc);
        acc = MFMA16(al0, bh0, acc);
        acc = MFMA16(al1, bh1, acc);
        #pragma unroll
        for (int reg = 0; reg < 4; ++reg){
            int row = 16 * w + quad * 4 + reg;
            Ab[t * 1024 + row * 16 + ln] = acc[reg];
        }
    }
    // nloc = colsum(kdec) = kdec^T @ ones — via 4 MFMAs against all-ones B frag
    // (replaces wave0-only 128-iter LDS loop with 8-way read conflicts)
    {
        short8 ones;
        #pragma unroll
        for (int j = 0; j < 8; ++j) ones[j] = (short)0x3F80;   // bf16 1.0
        f32x4 nacc = {0.f, 0.f, 0.f, 0.f};
        nacc = MFMA16(ah0, ones, nacc);
        nacc = MFMA16(ah1, ones, nacc);
        nacc = MFMA16(al0, ones, nacc);
        nacc = MFMA16(al1, ones, nacc);
        if (ln == 0){
            #pragma unroll
            for (int reg = 0; reg < 4; ++reg)
                nloc_ws[((size_t)(s * NT + ct)) * DK + 16 * w + quad * 4 + reg] = nacc[reg];
        }
    }
}

// ===================== Stage B: sequential combine (fp32) =====================
// grid (16, BH): scalar per-thread scan, 4 blocks/CU instead of 1.
__global__ __launch_bounds__(256) void stageB_kernel(
    const float* __restrict__ A_ws, const float* __restrict__ nloc_ws,
    const float* __restrict__ fl_ws, const float* __restrict__ mloc_ws,
    float* __restrict__ Cws, float* __restrict__ nws, float* __restrict__ mws,
    int NT)
{
    const int vb = blockIdx.x, s = blockIdx.y, tid = threadIdx.x;
    __shared__ float decs[64], scs[64];

    if (tid < 64){
        float fl = fl_ws[s * NT + tid];
        float ml = mloc_ws[s * NT + tid];
        float F = fl, G = ml;
        #pragma unroll
        for (int off = 1; off < 64; off <<= 1){
            float Fp = __shfl_up(F, off);
            float Gp = __shfl_up(G, off);
            if (tid >= off){ G = fmaxf(Gp + F, G); F = Fp + F; }
        }
        float m_next = fmaxf(F, G);
        float m_cur  = __shfl_up(m_next, 1);
        if (tid == 0) m_cur = 0.f;
        decs[tid] = exp2f(fl + m_cur - m_next);
        scs[tid]  = exp2f(ml - m_next);
        if (vb == 0) mws[s * NT + tid] = m_cur;
    }
    __syncthreads();

    const size_t base = (size_t)s * NT * 4096 + (size_t)vb * 256 + tid;
    const float* Ab = A_ws + base;
    float*       Cb = Cws  + base;
    const bool do_n = (vb == 0) && (tid < 64);

    float C = 0.f, nreg = 0.f;
    float p[8], nl[8];
    #pragma unroll
    for (int i = 0; i < 8; ++i){ p[i] = Ab[(size_t)i * 4096]; nl[i] = 0.f; }
    if (do_n){
        #pragma unroll
        for (int i = 0; i < 8; ++i) nl[i] = nloc_ws[((size_t)(s * NT + i)) * DK + tid];
    }

    for (int t0 = 0; t0 < NT; t0 += 8){
        float qv[8], nq[8];
        const int tn = t0 + 8;
        #pragma unroll
        for (int i = 0; i < 8; ++i)
            qv[i] = (tn + i < NT) ? Ab[(size_t)(tn + i) * 4096] : 0.f;
        #pragma unroll
        for (int i = 0; i < 8; ++i) nq[i] = 0.f;
        if (do_n){
            #pragma unroll
            for (int i = 0; i < 8; ++i)
                if (tn + i < NT) nq[i] = nloc_ws[((size_t)(s * NT + tn + i)) * DK + tid];
        }
        #pragma unroll
        for (int i = 0; i < 8; ++i){
            const int t = t0 + i;
            Cb[(size_t)t * 4096] = C;
            if (do_n) nws[((size_t)(s * NT + t)) * DK + tid] = nreg;
            const float d = decs[t], sc = scs[t];
            C = C * d + p[i] * sc;
            if (do_n) nreg = nreg * d + nl[i] * sc;
        }
        #pragma unroll
        for (int i = 0; i < 8; ++i){ p[i] = qv[i]; nl[i] = nq[i]; }
    }
}

// ===================== Pass 2: per-chunk outputs (split-bf16 MFMA) ==============
// LDS cut 56 KB -> ~38 KB (4 aliased slabs) => 4 blocks/CU (was 2).
__global__ __launch_bounds__(256, 4) void pass2_kernel(
    const float* __restrict__ qg, const float* __restrict__ kg, const float* __restrict__ vg,
    const float* __restrict__ ig, const float* __restrict__ fg,
    const float* __restrict__ Cws, const float* __restrict__ nws, const float* __restrict__ mws,
    float* __restrict__ out, int T, int NT)
{
    const int ct = blockIdx.x, s = blockIdx.y, tid = threadIdx.x;
    const int w = tid >> 6, lane = tid & 63, ln = lane & 15, quad = lane >> 4;
    const int q8 = quad * 8;

    __shared__ __align__(16) ushort_t bufA[BT * PAD];  // q_hi [row][k]  -> Z [row][col] (ZSW)
    __shared__ __align__(16) ushort_t bufB[BT * PAD];  // q_lo [row][k]  -> v^T hi [vdim][row] (SWZ)
    __shared__ __align__(16) ushort_t bufC[BT * PAD];  // k_hi (SWZ)     -> C^T hi [vdim][k] (SWZ)
    __shared__ __align__(16) ushort_t bufD[BT * PAD];  // k_lo (SWZ)     -> C^T lo (SWZ)
    __shared__ float colterm[BT], Mr[BT], rowfac[BT], dncl[BT];
    __shared__ float nsh[DK], qn[BT], rowsum[BT];

    const size_t rowbase = (size_t)s * T + (size_t)ct * BT;
    const float* qc = qg + rowbase * DK;
    const float* kc = kg + rowbase * DK;
    const float* vc = vg + rowbase * DV;
    const float* Cc = Cws + ((size_t)(s * NT + ct)) * 4096;   // slab-major
    const float* nc = nws + ((size_t)(s * NT + ct)) * DK;
    const float m   = mws[s * NT + ct];

    // global loads in flight
    float4 qr[4], kr4[4], vr[4], Cr[4];
    #pragma unroll
    for (int i = 0; i < 4; ++i){
        int idx = i * 1024 + tid * 4;
        qr[i]  = *(const float4*)(qc + idx);
        kr4[i] = *(const float4*)(kc + idx);
        vr[i]  = *(const float4*)(vc + idx);
        Cr[i]  = *(const float4*)(Cc + idx);
    }
    // gates
    if (tid < 64){
        float b = logsig_log2e(fg[rowbase + tid]);
        #pragma unroll
        for (int off = 1; off < 64; off <<= 1){
            float y = __shfl_up(b, off);
            if (tid >= off) b += y;
        }
        float a = ig[rowbase + tid] * LOG2E_F - b;
        float p = a;
        #pragma unroll
        for (int off = 1; off < 64; off <<= 1){
            float y = __shfl_up(p, off);
            if (tid >= off) p = fmaxf(p, y);
        }
        float M = fmaxf(m, p);
        colterm[tid] = a;
        Mr[tid] = M;
        rowfac[tid] = SCALE * exp2f(m - M);
        dncl[tid] = exp2f(-(b + M));
        nsh[tid] = nc[tid];
    }
    // stage q (natural, split) and k (natural-swz, split)
    #pragma unroll
    for (int i = 0; i < 4; ++i){
        int idx = i * 1024 + tid * 4;
        int r = idx >> 6, c0 = idx & 63;
        float qv[4] = {qr[i].x, qr[i].y, qr[i].z, qr[i].w};
        float kv[4] = {kr4[i].x, kr4[i].y, kr4[i].z, kr4[i].w};
        ushort4v qh4, ql4, kh4, kl4;
        #pragma unroll
        for (int j = 0; j < 4; ++j){
            ushort_t h, l;
            split_bf(qv[j], h, l); qh4[j] = h; ql4[j] = l;
            split_bf(kv[j], h, l); kh4[j] = h; kl4[j] = l;
        }
        *(ushort4v*)&bufA[LIN(r, c0)] = qh4;
        *(ushort4v*)&bufB[LIN(r, c0)] = ql4;
        *(ushort4v*)&bufC[SWZ(r, c0)] = kh4;   // swz flips bits 3,4 only: 4-elem vec stays contiguous
        *(ushort4v*)&bufD[SWZ(r, c0)] = kl4;
    }
    __syncthreads();   // #1: q,k staged; gates visible

    const int mrow = 16 * w + ln;
    short8 ah0 = *(const short8*)&bufA[LIN(mrow, q8)];
    short8 ah1 = *(const short8*)&bufA[LIN(mrow, 32 + q8)];
    short8 al0 = *(const short8*)&bufB[LIN(mrow, q8)];
    short8 al1 = *(const short8*)&bufB[LIN(mrow, 32 + q8)];

    // qn[mrow] = sum_k q*n   (fp32, from recombined fragments)
    {
        float p = 0.f;
        #pragma unroll
        for (int j = 0; j < 8; ++j){
            float qv0 = bf2f((ushort_t)ah0[j]) + bf2f((ushort_t)al0[j]);
            float qv1 = bf2f((ushort_t)ah1[j]) + bf2f((ushort_t)al1[j]);
            p = fmaf(qv0, nsh[q8 + j], p);
            p = fmaf(qv1, nsh[32 + q8 + j], p);
        }
        p += __shfl_xor(p, 16);
        p += __shfl_xor(p, 32);
        if (quad == 0) qn[mrow] = p;
    }
    __syncthreads();   // #2: all q-fragment reads done -> bufA/bufB reusable

    // stage v^T hi into bufB (from registers; swizzled scatter ~2-way)
    #pragma unroll
    for (int i = 0; i < 4; ++i){
        int idx = i * 1024 + tid * 4;
        int r = idx >> 6, c0 = idx & 63;
        float vv[4] = {vr[i].x, vr[i].y, vr[i].z, vr[i].w};
        #pragma unroll
        for (int j = 0; j < 4; ++j) bufB[SWZ(c0 + j, r)] = f2bf(vv[j]);
    }

    // ---- S = q @ k^T (3-product split) ----
    f32x4 sacc[4];
    #pragma unroll
    for (int t = 0; t < 4; ++t){
        sacc[t] = (f32x4){0.f, 0.f, 0.f, 0.f};
        short8 bh0 = *(const short8*)&bufC[SWZ(16 * t + ln, q8)];
        short8 bh1 = *(const short8*)&bufC[SWZ(16 * t + ln, 32 + q8)];
        short8 bl0 = *(const short8*)&bufD[SWZ(16 * t + ln, q8)];
        short8 bl1 = *(const short8*)&bufD[SWZ(16 * t + ln, 32 + q8)];
        sacc[t] = MFMA16(ah0, bh0, sacc[t]);
        sacc[t] = MFMA16(ah1, bh1, sacc[t]);
        sacc[t] = MFMA16(ah0, bl0, sacc[t]);
        sacc[t] = MFMA16(ah1, bl1, sacc[t]);
        sacc[t] = MFMA16(al0, bh0, sacc[t]);
        sacc[t] = MFMA16(al1, bh1, sacc[t]);
    }
    // scale + mask + rowsum (fp32-exact) + write Z into bufA (ZSW)
    {
        float rsum[4] = {0.f, 0.f, 0.f, 0.f};
        float Mrv[4];
        #pragma unroll
        for (int reg = 0; reg < 4; ++reg) Mrv[reg] = Mr[16 * w + quad * 4 + reg];
        #pragma unroll
        for (int t = 0; t < 4; ++t){
            int c = 16 * t + ln;
            float cterm = colterm[c];
            #pragma unroll
            for (int reg = 0; reg < 4; ++reg){
                int r = 16 * w + quad * 4 + reg;
                float vS = (c <= r) ? sacc[t][reg] * SCALE * exp2f(cterm - Mrv[reg]) : 0.f;
                bufA[ZSW(r, c)] = f2bf(vS);
                rsum[reg] += vS;
            }
        }
        #pragma unroll
        for (int off = 1; off < 16; off <<= 1){
            #pragma unroll
            for (int reg = 0; reg < 4; ++reg) rsum[reg] += __shfl_xor(rsum[reg], off);
        }
        if (ln == 0){
            #pragma unroll
            for (int reg = 0; reg < 4; ++reg) rowsum[16 * w + quad * 4 + reg] = rsum[reg];
        }
    }
    __syncthreads();   // #3: k reads done, Z + v^T staged

    // stage C^T (split) into bufC/bufD (swizzled scatter ~2-way)
    #pragma unroll
    for (int i = 0; i < 4; ++i){
        int idx = i * 1024 + tid * 4;
        int vsl = idx >> 10, krow = (idx >> 4) & 63, ci = idx & 15;
        int v0 = vsl * 16 + ci;
        float cv[4] = {Cr[i].x, Cr[i].y, Cr[i].z, Cr[i].w};
        #pragma unroll
        for (int j = 0; j < 4; ++j){
            ushort_t h, l;
            split_bf(cv[j], h, l);
            bufC[SWZ(v0 + j, krow)] = h;
            bufD[SWZ(v0 + j, krow)] = l;
        }
    }
    __syncthreads();   // #4

    // ---- acc = (q @ C) * rowfac ----
    f32x4 acc[4];
    #pragma unroll
    for (int t = 0; t < 4; ++t){
        acc[t] = (f32x4){0.f, 0.f, 0.f, 0.f};
        short8 bh0 = *(const short8*)&bufC[SWZ(16 * t + ln, q8)];
        short8 bh1 = *(const short8*)&bufC[SWZ(16 * t + ln, 32 + q8)];
        short8 bl0 = *(const short8*)&bufD[SWZ(16 * t + ln, q8)];
        short8 bl1 = *(const short8*)&bufD[SWZ(16 * t + ln, 32 + q8)];
        acc[t] = MFMA16(ah0, bh0, acc[t]);
        acc[t] = MFMA16(ah1, bh1, acc[t]);
        acc[t] = MFMA16(ah0, bl0, acc[t]);
        acc[t] = MFMA16(ah1, bl1, acc[t]);
        acc[t] = MFMA16(al0, bh0, acc[t]);
        acc[t] = MFMA16(al1, bh1, acc[t]);
    }
    float rf[4], inv[4];
    #pragma unroll
    for (int reg = 0; reg < 4; ++reg){
        int r = 16 * w + quad * 4 + reg;
        rf[reg] = rowfac[r];
        float dn = fabsf(rf[reg] * qn[r] + rowsum[r]);
        inv[reg] = 1.f / fmaxf(dn, dncl[r]);
    }
    #pragma unroll
    for (int t = 0; t < 4; ++t){
        #pragma unroll
        for (int reg = 0; reg < 4; ++reg) acc[t][reg] *= rf[reg];
    }
    // ---- += S @ v ----
    short8 az0 = *(const short8*)&bufA[ZSW(mrow, q8)];
    short8 az1 = *(const short8*)&bufA[ZSW(mrow, 32 + q8)];
    #pragma unroll
    for (int t = 0; t < 4; ++t){
        short8 bh0 = *(const short8*)&bufB[SWZ(16 * t + ln, q8)];
        short8 bh1 = *(const short8*)&bufB[SWZ(16 * t + ln, 32 + q8)];
        acc[t] = MFMA16(az0, bh0, acc[t]);
        acc[t] = MFMA16(az1, bh1, acc[t]);
    }
    // epilogue
    #pragma unroll
    for (int t = 0; t < 4; ++t){
        int c = 16 * t + ln;
        #pragma unroll
        for (int reg = 0; reg < 4; ++reg){
            int r = 16 * w + quad * 4 + reg;
            out[(rowbase + r) * DV + c] = acc[t][reg] * inv[reg];
        }
    }
}

// ---------------- Fallback: fused sequential fp32 (no workspace) ----------------
__global__ __launch_bounds__(256) void fused_kernel(
    const float* __restrict__ qg, const float* __restrict__ kg, const float* __restrict__ vg,
    const float* __restrict__ ig, const float* __restrict__ fg,
    float* __restrict__ out, int T, int NT)
{
    const int s = blockIdx.x;
    const int tid = threadIdx.x;
    const int lane = tid & 63;

    __shared__ float X[BT][DK + 1];
    __shared__ float Y[BT][DK + 1];
    __shared__ float Cb[DK][DV];
    __shared__ __hip_bfloat16 Zh[BT][BT];
    __shared__ float colterm[BT], Mr[BT], rowfac[BT], dncl[BT], gscale[BT];
    __shared__ float nsh[DK], qn[BT], rowsum[BT], denom[BT];
    __shared__ float sh_dec;

    const float* qseq = qg + (size_t)s * T * DK;
    const float* kseq = kg + (size_t)s * T * DK;
    const float* vseq = vg + (size_t)s * T * DV;
    const float* iseq = ig + (size_t)s * T;
    const float* fseq = fg + (size_t)s * T;

    for (int idx = tid; idx < DK * DV; idx += 256) Cb[idx >> 6][idx & 63] = 0.f;
    if (tid < 64) nsh[lane] = 0.f;
    float m = 0.f;
    __syncthreads();

    const int r0 = (tid >> 4) * 4;
    const int c0 = (tid & 15) * 4;
    const int v0 = c0;

    for (int t = 0; t < NT; ++t){
        const size_t rb = (size_t)t * BT;
        if (tid < 64){
            float b = logsig_log2e(fseq[rb + lane]);
            #pragma unroll
            for (int off = 1; off < 64; off <<= 1){
                float y = __shfl_up(b, off);
                if (lane >= off) b += y;
            }
            float f_last = __shfl(b, 63);
            float a = iseq[rb + lane] * LOG2E_F - b;
            float p = a;
            #pragma unroll
            for (int off = 1; off < 64; off <<= 1){
                float y = __shfl_up(p, off);
                if (lane >= off) p = fmaxf(p, y);
            }
            float M = fmaxf(m, p);
            colterm[lane] = a;
            Mr[lane] = M;
            rowfac[lane] = SCALE * exp2f(m - M);
            dncl[lane] = exp2f(-(b + M));
            float g = a + f_last;
            float gm = g;
            #pragma unroll
            for (int off = 32; off > 0; off >>= 1) gm = fmaxf(gm, __shfl_xor(gm, off));
            float m_next = fmaxf(f_last + m, gm);
            gscale[lane] = exp2f(g - m_next);
            if (tid == 0) sh_dec = exp2f(f_last + m - m_next);
            m = m_next;
        }
        #pragma unroll
        for (int base = 0; base < BT * DK; base += 1024){
            int idx = base + tid * 4;
            int r = idx >> 6, c = idx & 63;
            float4 a4 = *(const float4*)(qseq + rb * DK + idx);
            X[r][c] = a4.x; X[r][c+1] = a4.y; X[r][c+2] = a4.z; X[r][c+3] = a4.w;
            float4 b4 = *(const float4*)(kseq + rb * DK + idx);
            Y[r][c] = b4.x; Y[r][c+1] = b4.y; Y[r][c+2] = b4.z; Y[r][c+3] = b4.w;
        }
        __syncthreads();

        float sacc[4][4] = {};
        for (int x = 0; x < DK; ++x){
            float xr[4], yc[4];
            #pragma unroll
            for (int j = 0; j < 4; ++j) xr[j] = X[r0 + j][x];
            #pragma unroll
            for (int j = 0; j < 4; ++j) yc[j] = Y[c0 + j][x];
            #pragma unroll
            for (int j = 0; j < 4; ++j)
                #pragma unroll
                for (int jj = 0; jj < 4; ++jj)
                    sacc[j][jj] = fmaf(xr[j], yc[jj], sacc[j][jj]);
        }
        float rs[4];
        #pragma unroll
        for (int j = 0; j < 4; ++j){
            int r = r0 + j;
            float Mrv = Mr[r];
            float acc = 0.f;
            #pragma unroll
            for (int jj = 0; jj < 4; ++jj){
                int c = c0 + jj;
                float vS = (c <= r) ? sacc[j][jj] * SCALE * exp2f(colterm[c] - Mrv) : 0.f;
                Zh[r][c] = __float2bfloat16(vS);
                acc += vS;
            }
            rs[j] = acc;
        }
        #pragma unroll
        for (int off = 1; off < 16; off <<= 1){
            #pragma unroll
            for (int j = 0; j < 4; ++j) rs[j] += __shfl_xor(rs[j], off);
        }
        if ((tid & 15) == 0){
            #pragma unroll
            for (int j = 0; j < 4; ++j) rowsum[r0 + j] = rs[j];
        }
        float acc1[4][4] = {};
        for (int x = 0; x < DK; ++x){
            float xr[4], yv[4];
            #pragma unroll
            for (int j = 0; j < 4; ++j) xr[j] = X[r0 + j][x];
            #pragma unroll
            for (int j = 0; j < 4; ++j) yv[j] = Cb[x][v0 + j];
            #pragma unroll
            for (int j = 0; j < 4; ++j)
                #pragma unroll
                for (int jj = 0; jj < 4; ++jj)
                    acc1[j][jj] = fmaf(xr[j], yv[jj], acc1[j][jj]);
        }
        if (tid < 64){
            float acc = 0.f;
            for (int x = 0; x < DK; ++x) acc = fmaf(X[lane][x], nsh[x], acc);
            qn[lane] = acc;
        }
        __syncthreads();

        #pragma unroll
        for (int base = 0; base < BT * DV; base += 1024){
            int idx = base + tid * 4;
            int r = idx >> 6, c = idx & 63;
            float4 a4 = *(const float4*)(vseq + rb * DV + idx);
            X[r][c] = a4.x; X[r][c+1] = a4.y; X[r][c+2] = a4.z; X[r][c+3] = a4.w;
        }
        if (tid < 64){
            float dn = fabsf(rowfac[lane] * qn[lane] + rowsum[lane]);
            denom[lane] = fmaxf(dn, dncl[lane]);
        }
        __syncthreads();

        float acc2[4][4] = {};
        for (int c = 0; c < BT; ++c){
            float zr[4], xv[4];
            #pragma unroll
            for (int j = 0; j < 4; ++j) zr[j] = __bfloat162float(Zh[r0 + j][c]);
            #pragma unroll
            for (int j = 0; j < 4; ++j) xv[j] = X[c][v0 + j];
            #pragma unroll
            for (int j = 0; j < 4; ++j)
                #pragma unroll
                for (int jj = 0; jj < 4; ++jj)
                    acc2[j][jj] = fmaf(zr[j], xv[jj], acc2[j][jj]);
        }
        #pragma unroll
        for (int j = 0; j < 4; ++j){
            int r = r0 + j;
            float rf = rowfac[r];
            float inv = 1.f / denom[r];
            float4 h4;
            h4.x = (acc1[j][0] * rf + acc2[j][0]) * inv;
            h4.y = (acc1[j][1] * rf + acc2[j][1]) * inv;
            h4.z = (acc1[j][2] * rf + acc2[j][2]) * inv;
            h4.w = (acc1[j][3] * rf + acc2[j][3]) * inv;
            *(float4*)(out + ((size_t)s * T + rb + r) * DV + v0) = h4;
        }
        {
            float dec = sh_dec;
            float cr[4][4];
            #pragma unroll
            for (int j = 0; j < 4; ++j)
                #pragma unroll
                for (int jj = 0; jj < 4; ++jj)
                    cr[j][jj] = Cb[r0 + j][c0 + jj] * dec;
            for (int c = 0; c < BT; ++c){
                float gs = gscale[c];
                float kd[4], xv[4];
                #pragma unroll
                for (int j = 0; j < 4; ++j) kd[j] = Y[c][r0 + j] * gs;
                #pragma unroll
                for (int jj = 0; jj < 4; ++jj) xv[jj] = X[c][c0 + jj];
                #pragma unroll
                for (int j = 0; j < 4; ++j)
                    #pragma unroll
                    for (int jj = 0; jj < 4; ++jj)
                        cr[j][jj] = fmaf(kd[j], xv[jj], cr[j][jj]);
            }
            #pragma unroll
            for (int j = 0; j < 4; ++j)
                #pragma unroll
                for (int jj = 0; jj < 4; ++jj)
                    Cb[r0 + j][c0 + jj] = cr[j][jj];
        }
        if (tid < 64){
            float acc = 0.f;
            for (int c = 0; c < BT; ++c) acc = fmaf(Y[c][lane], gscale[c], acc);
            nsh[lane] = nsh[lane] * sh_dec + acc;
        }
        __syncthreads();
    }
}

extern "C" void kernel_launch(void* const* d_in, const int* in_sizes, int n_in,
                              void* d_out, int out_size, void* d_ws, size_t ws_size,
                              hipStream_t stream)
{
    const float* q  = (const float*)d_in[0];
    const float* k  = (const float*)d_in[1];
    const float* v  = (const float*)d_in[2];
    const float* ii = (const float*)d_in[3];
    const float* ff = (const float*)d_in[4];
    float* out = (float*)d_out;

    const int T  = 4096;
    const int BH = in_sizes[3] / T;
    const int NT = T / BT;

    const size_t szC  = (size_t)BH * NT * DK * DV * sizeof(float);
    const size_t szA  = szC;
    const size_t szn  = (size_t)BH * NT * DK * sizeof(float);
    const size_t szs  = (size_t)BH * NT * sizeof(float);

    const size_t need_new = szA + szC + 2 * szn + 3 * szs;

    if (ws_size >= need_new){
        char* p = (char*)d_ws;
        float* A_ws    = (float*)p;            p += szA;
        float* Cws     = (float*)p;            p += szC;
        float* nloc_ws = (float*)p;            p += szn;
        float* nws     = (float*)p;            p += szn;
        float* fl_ws   = (float*)p;            p += szs;
        float* mloc_ws = (float*)p;            p += szs;
        float* mws     = (float*)p;
        stageA_kernel<<<dim3(NT, BH), 256, 0, stream>>>(k, v, ii, ff, A_ws, nloc_ws, fl_ws, mloc_ws, T, NT);
        stageB_kernel<<<dim3(16, BH), 256, 0, stream>>>(A_ws, nloc_ws, fl_ws, mloc_ws, Cws, nws, mws, NT);
        pass2_kernel<<<dim3(NT, BH), 256, 0, stream>>>(q, k, v, ii, ff, Cws, nws, mws, out, T, NT);
    } else {
        fused_kernel<<<dim3(BH), 256, 0, stream>>>(q, k, v, ii, ff, out, T, NT);
    }
}

// Round 2
// 292.093 us; speedup vs baseline: 1.0653x; 1.0010x over previous
//
#include <hip/hip_runtime.h>
#include <hip/hip_bf16.h>
#include <math.h>

#define LOG2E_F 1.4426950408889634f

static constexpr int BT = 64;
static constexpr int DK = 64;
static constexpr int DV = 64;
static constexpr float SCALE = 0.125f;
static constexpr int PAD = 72;   // ushort row stride: 144 B, 16B-aligned; rotates banks by 4/row

typedef unsigned short ushort_t;
typedef __attribute__((ext_vector_type(8))) short short8;
typedef __attribute__((ext_vector_type(4))) float f32x4;
typedef __attribute__((ext_vector_type(4))) ushort_t ushort4v;

#define MFMA16(a, b, c) __builtin_amdgcn_mfma_f32_16x16x32_bf16((a), (b), (c), 0, 0, 0)

// [64][PAD] ushort slab indexers.
// SWZ: XOR-swizzle minor index (bits 3,4) keyed on major index — spreads
// transposed scalar writes across banks while keeping 8-elem (16B) fragment
// reads contiguous (XOR flips whole 8-blocks).
__device__ __forceinline__ int SWZ(int a, int b){ return a * PAD + (b ^ (((a >> 3) & 3) << 3)); }
// Z slab: swizzle column keyed on row bits 2,3 (write lanes vary col within quads)
__device__ __forceinline__ int ZSW(int r, int c){ return r * PAD + (c ^ (((r >> 2) & 3) << 3)); }
__device__ __forceinline__ int LIN(int r, int c){ return r * PAD + c; }

__device__ __forceinline__ float logsig_log2e(float x){
    float l = (x >= 0.f) ? (-log1pf(expf(-x))) : (x - log1pf(expf(x)));
    return l * LOG2E_F;
}
__device__ __forceinline__ ushort_t f2bf(float x){   // RNE f32 -> bf16 bits
    unsigned u = __builtin_bit_cast(unsigned, x);
    unsigned r = u + 0x7FFFu + ((u >> 16) & 1u);
    return (ushort_t)(r >> 16);
}
__device__ __forceinline__ float bf2f(ushort_t u){
    return __builtin_bit_cast(float, ((unsigned)u) << 16);
}
__device__ __forceinline__ void split_bf(float x, ushort_t& h, ushort_t& l){
    h = f2bf(x);
    l = f2bf(x - bf2f(h));
}

// ===================== Stage A: per-chunk local state (split-bf16 MFMA) ==========
// A workspace layout: [(s*NT+ct)] slab of 4096 floats, plain [vdim][kdim]:
//   A[v*64 + k]  — lets each lane store its f32x4 acc as ONE coalesced float4.
__global__ __launch_bounds__(256, 4) void stageA_kernel(
    const float* __restrict__ kg, const float* __restrict__ vg,
    const float* __restrict__ ig, const float* __restrict__ fg,
    float* __restrict__ A_ws, float* __restrict__ nloc_ws,
    float* __restrict__ fl_ws, float* __restrict__ mloc_ws,
    int T, int NT)
{
    const int ct = blockIdx.x, s = blockIdx.y, tid = threadIdx.x;
    const int w = tid >> 6, lane = tid & 63, ln = lane & 15, quad = lane >> 4;
    const int q8 = quad * 8;

    __shared__ __align__(16) ushort_t kth[BT * PAD];  // kdec^T hi  [kdim][row] swz
    __shared__ __align__(16) ushort_t ktl[BT * PAD];  // kdec^T lo
    __shared__ __align__(16) ushort_t vth[BT * PAD];  // v^T hi     [vdim][row] swz
    __shared__ __align__(16) ushort_t vtl[BT * PAD];  // v^T lo
    __shared__ float gsc[BT];

    const size_t rowbase = (size_t)s * T + (size_t)ct * BT;
    const float* kc = kg + rowbase * DK;
    const float* vc = vg + rowbase * DV;

    float4 kr[4], vr[4];
    #pragma unroll
    for (int i = 0; i < 4; ++i){
        int idx = i * 1024 + tid * 4;
        kr[i] = *(const float4*)(kc + idx);
        vr[i] = *(const float4*)(vc + idx);
    }
    if (tid < 64){
        float b = logsig_log2e(fg[rowbase + tid]);
        #pragma unroll
        for (int off = 1; off < 64; off <<= 1){
            float y = __shfl_up(b, off);
            if (tid >= off) b += y;
        }
        float f_last = __shfl(b, 63);
        float a = ig[rowbase + tid] * LOG2E_F - b;
        float p = a;
        #pragma unroll
        for (int off = 32; off > 0; off >>= 1) p = fmaxf(p, __shfl_xor(p, off));
        gsc[tid] = exp2f(a - p);
        if (tid == 0){ fl_ws[s * NT + ct] = f_last; mloc_ws[s * NT + ct] = f_last + p; }
    }
    __syncthreads();
    // transpose-stage split-bf16 (k scaled by gsc[row]); swizzled scatter (~2-way)
    #pragma unroll
    for (int i = 0; i < 4; ++i){
        int idx = i * 1024 + tid * 4;
        int r = idx >> 6, c0 = idx & 63;
        float g = gsc[r];
        float kv[4] = {kr[i].x * g, kr[i].y * g, kr[i].z * g, kr[i].w * g};
        float vv[4] = {vr[i].x, vr[i].y, vr[i].z, vr[i].w};
        #pragma unroll
        for (int j = 0; j < 4; ++j){
            ushort_t h, l;
            split_bf(kv[j], h, l); kth[SWZ(c0 + j, r)] = h; ktl[SWZ(c0 + j, r)] = l;
            split_bf(vv[j], h, l); vth[SWZ(c0 + j, r)] = h; vtl[SWZ(c0 + j, r)] = l;
        }
    }
    __syncthreads();

    const int m = 16 * w + ln;
    short8 ah0 = *(const short8*)&kth[SWZ(m, q8)];
    short8 ah1 = *(const short8*)&kth[SWZ(m, 32 + q8)];
    short8 al0 = *(const short8*)&ktl[SWZ(m, q8)];
    short8 al1 = *(const short8*)&ktl[SWZ(m, 32 + q8)];
    float* Ab = A_ws + (size_t)(s * NT + ct) * 4096;
    #pragma unroll
    for (int t = 0; t < 4; ++t){
        f32x4 acc = {0.f, 0.f, 0.f, 0.f};
        short8 bh0 = *(const short8*)&vth[SWZ(16 * t + ln, q8)];
        short8 bh1 = *(const short8*)&vth[SWZ(16 * t + ln, 32 + q8)];
        short8 bl0 = *(const short8*)&vtl[SWZ(16 * t + ln, q8)];
        short8 bl1 = *(const short8*)&vtl[SWZ(16 * t + ln, 32 + q8)];
        acc = MFMA16(ah0, bh0, acc);
        acc = MFMA16(ah1, bh1, acc);
        acc = MFMA16(ah0, bl0, acc);
        acc = MFMA16(ah1, bl1, acc);
        acc = MFMA16(al0, bh0, acc);
        acc = MFMA16(al1, bh1, acc);
        // acc[reg] = A[k = 16w + quad*4 + reg][v = 16t + ln]
        // store as [v][k]: one coalesced float4 per (lane, t)
        *(f32x4*)(Ab + ((16 * t + ln) << 6) + 16 * w + quad * 4) = acc;
    }
    // nloc = colsum(kdec) = kdec^T @ ones — via 4 MFMAs against all-ones B frag
    {
        short8 ones;
        #pragma unroll
        for (int j = 0; j < 8; ++j) ones[j] = (short)0x3F80;   // bf16 1.0
        f32x4 nacc = {0.f, 0.f, 0.f, 0.f};
        nacc = MFMA16(ah0, ones, nacc);
        nacc = MFMA16(ah1, ones, nacc);
        nacc = MFMA16(al0, ones, nacc);
        nacc = MFMA16(al1, ones, nacc);
        if (ln == 0){
            #pragma unroll
            for (int reg = 0; reg < 4; ++reg)
                nloc_ws[((size_t)(s * NT + ct)) * DK + 16 * w + quad * 4 + reg] = nacc[reg];
        }
    }
}

// ===================== Stage B: sequential combine (fp32) =====================
// Pure elementwise scan over the 4096-float slabs — layout-agnostic.
__global__ __launch_bounds__(256) void stageB_kernel(
    const float* __restrict__ A_ws, const float* __restrict__ nloc_ws,
    const float* __restrict__ fl_ws, const float* __restrict__ mloc_ws,
    float* __restrict__ Cws, float* __restrict__ nws, float* __restrict__ mws,
    int NT)
{
    const int vb = blockIdx.x, s = blockIdx.y, tid = threadIdx.x;
    __shared__ float decs[64], scs[64];

    if (tid < 64){
        float fl = fl_ws[s * NT + tid];
        float ml = mloc_ws[s * NT + tid];
        float F = fl, G = ml;
        #pragma unroll
        for (int off = 1; off < 64; off <<= 1){
            float Fp = __shfl_up(F, off);
            float Gp = __shfl_up(G, off);
            if (tid >= off){ G = fmaxf(Gp + F, G); F = Fp + F; }
        }
        float m_next = fmaxf(F, G);
        float m_cur  = __shfl_up(m_next, 1);
        if (tid == 0) m_cur = 0.f;
        decs[tid] = exp2f(fl + m_cur - m_next);
        scs[tid]  = exp2f(ml - m_next);
        if (vb == 0) mws[s * NT + tid] = m_cur;
    }
    __syncthreads();

    const size_t base = (size_t)s * NT * 4096 + (size_t)vb * 256 + tid;
    const float* Ab = A_ws + base;
    float*       Cb = Cws  + base;
    const bool do_n = (vb == 0) && (tid < 64);

    float C = 0.f, nreg = 0.f;
    float p[8], nl[8];
    #pragma unroll
    for (int i = 0; i < 8; ++i){ p[i] = Ab[(size_t)i * 4096]; nl[i] = 0.f; }
    if (do_n){
        #pragma unroll
        for (int i = 0; i < 8; ++i) nl[i] = nloc_ws[((size_t)(s * NT + i)) * DK + tid];
    }

    for (int t0 = 0; t0 < NT; t0 += 8){
        float qv[8], nq[8];
        const int tn = t0 + 8;
        #pragma unroll
        for (int i = 0; i < 8; ++i)
            qv[i] = (tn + i < NT) ? Ab[(size_t)(tn + i) * 4096] : 0.f;
        #pragma unroll
        for (int i = 0; i < 8; ++i) nq[i] = 0.f;
        if (do_n){
            #pragma unroll
            for (int i = 0; i < 8; ++i)
                if (tn + i < NT) nq[i] = nloc_ws[((size_t)(s * NT + tn + i)) * DK + tid];
        }
        #pragma unroll
        for (int i = 0; i < 8; ++i){
            const int t = t0 + i;
            Cb[(size_t)t * 4096] = C;
            if (do_n) nws[((size_t)(s * NT + t)) * DK + tid] = nreg;
            const float d = decs[t], sc = scs[t];
            C = C * d + p[i] * sc;
            if (do_n) nreg = nreg * d + nl[i] * sc;
        }
        #pragma unroll
        for (int i = 0; i < 8; ++i){ p[i] = qv[i]; nl[i] = nq[i]; }
    }
}

// ===================== Pass 2: per-chunk outputs (split-bf16 MFMA) ==============
// q loads DIRECTLY into fragment registers (no LDS round-trip); C arrives in
// [v][k] layout so its staging is a natural-order vectorized copy. 3 barriers.
__global__ __launch_bounds__(256, 4) void pass2_kernel(
    const float* __restrict__ qg, const float* __restrict__ kg, const float* __restrict__ vg,
    const float* __restrict__ ig, const float* __restrict__ fg,
    const float* __restrict__ Cws, const float* __restrict__ nws, const float* __restrict__ mws,
    float* __restrict__ out, int T, int NT)
{
    const int ct = blockIdx.x, s = blockIdx.y, tid = threadIdx.x;
    const int w = tid >> 6, lane = tid & 63, ln = lane & 15, quad = lane >> 4;
    const int q8 = quad * 8;

    __shared__ __align__(16) ushort_t bufA[BT * PAD];  // k_hi [row][k] (SWZ) -> C_hi [v][k] (SWZ)
    __shared__ __align__(16) ushort_t bufB[BT * PAD];  // k_lo (SWZ)          -> C_lo (SWZ)
    __shared__ __align__(16) ushort_t bufZ[BT * PAD];  // Z [row][col] (ZSW)
    __shared__ __align__(16) ushort_t bufV[BT * PAD];  // v^T hi [vdim][row] (SWZ)
    __shared__ float colterm[BT], Mr[BT], rowfac[BT], dncl[BT];
    __shared__ float nsh[DK], qn[BT], rowsum[BT];

    const size_t rowbase = (size_t)s * T + (size_t)ct * BT;
    const float* qc = qg + rowbase * DK;
    const float* kc = kg + rowbase * DK;
    const float* vc = vg + rowbase * DV;
    const float* Cc = Cws + ((size_t)(s * NT + ct)) * 4096;   // [v][k]
    const float* nc = nws + ((size_t)(s * NT + ct)) * DK;
    const float m   = mws[s * NT + ct];

    // ---- issue all global loads ----
    float4 kr4[4], vr[4];
    #pragma unroll
    for (int i = 0; i < 4; ++i){
        int idx = i * 1024 + tid * 4;
        kr4[i] = *(const float4*)(kc + idx);
        vr[i]  = *(const float4*)(vc + idx);
    }
    // q: each lane loads exactly its fragment elements (rows 16w+ln, two 8-float runs)
    const float* qrow = qc + (16 * w + ln) * DK;
    float4 qf0 = *(const float4*)(qrow + q8);
    float4 qf1 = *(const float4*)(qrow + q8 + 4);
    float4 qf2 = *(const float4*)(qrow + 32 + q8);
    float4 qf3 = *(const float4*)(qrow + 32 + q8 + 4);
    float4 Cr[4];
    #pragma unroll
    for (int i = 0; i < 4; ++i)
        Cr[i] = *(const float4*)(Cc + i * 1024 + tid * 4);

    // gates
    if (tid < 64){
        float b = logsig_log2e(fg[rowbase + tid]);
        #pragma unroll
        for (int off = 1; off < 64; off <<= 1){
            float y = __shfl_up(b, off);
            if (tid >= off) b += y;
        }
        float a = ig[rowbase + tid] * LOG2E_F - b;
        float p = a;
        #pragma unroll
        for (int off = 1; off < 64; off <<= 1){
            float y = __shfl_up(p, off);
            if (tid >= off) p = fmaxf(p, y);
        }
        float M = fmaxf(m, p);
        colterm[tid] = a;
        Mr[tid] = M;
        rowfac[tid] = SCALE * exp2f(m - M);
        dncl[tid] = exp2f(-(b + M));
        nsh[tid] = nc[tid];
    }
    // stage k (natural, split, SWZ vectorized writes)
    #pragma unroll
    for (int i = 0; i < 4; ++i){
        int idx = i * 1024 + tid * 4;
        int r = idx >> 6, c0 = idx & 63;
        float kv[4] = {kr4[i].x, kr4[i].y, kr4[i].z, kr4[i].w};
        ushort4v kh4, kl4;
        #pragma unroll
        for (int j = 0; j < 4; ++j){
            ushort_t h, l;
            split_bf(kv[j], h, l); kh4[j] = h; kl4[j] = l;
        }
        *(ushort4v*)&bufA[SWZ(r, c0)] = kh4;
        *(ushort4v*)&bufB[SWZ(r, c0)] = kl4;
    }
    __syncthreads();   // #1: k staged; gates visible

    // build q fragments in registers (exact f32 kept for qn)
    const int mrow = 16 * w + ln;
    float a0[8] = {qf0.x, qf0.y, qf0.z, qf0.w, qf1.x, qf1.y, qf1.z, qf1.w};
    float a1[8] = {qf2.x, qf2.y, qf2.z, qf2.w, qf3.x, qf3.y, qf3.z, qf3.w};
    short8 ah0, al0, ah1, al1;
    #pragma unroll
    for (int j = 0; j < 8; ++j){
        ushort_t h, l;
        split_bf(a0[j], h, l); ah0[j] = (short)h; al0[j] = (short)l;
        split_bf(a1[j], h, l); ah1[j] = (short)h; al1[j] = (short)l;
    }
    // qn[mrow] = sum_k q*n (exact f32 fragments)
    {
        float p = 0.f;
        #pragma unroll
        for (int j = 0; j < 8; ++j){
            p = fmaf(a0[j], nsh[q8 + j], p);
            p = fmaf(a1[j], nsh[32 + q8 + j], p);
        }
        p += __shfl_xor(p, 16);
        p += __shfl_xor(p, 32);
        if (quad == 0) qn[mrow] = p;
    }
    // stage v^T hi into bufV (overlaps with S phase; visible after sync #2)
    #pragma unroll
    for (int i = 0; i < 4; ++i){
        int idx = i * 1024 + tid * 4;
        int r = idx >> 6, c0 = idx & 63;
        float vv[4] = {vr[i].x, vr[i].y, vr[i].z, vr[i].w};
        #pragma unroll
        for (int j = 0; j < 4; ++j) bufV[SWZ(c0 + j, r)] = f2bf(vv[j]);
    }

    // ---- S = q @ k^T (3-product split) ----
    f32x4 sacc[4];
    #pragma unroll
    for (int t = 0; t < 4; ++t){
        sacc[t] = (f32x4){0.f, 0.f, 0.f, 0.f};
        short8 bh0 = *(const short8*)&bufA[SWZ(16 * t + ln, q8)];
        short8 bh1 = *(const short8*)&bufA[SWZ(16 * t + ln, 32 + q8)];
        short8 bl0 = *(const short8*)&bufB[SWZ(16 * t + ln, q8)];
        short8 bl1 = *(const short8*)&bufB[SWZ(16 * t + ln, 32 + q8)];
        sacc[t] = MFMA16(ah0, bh0, sacc[t]);
        sacc[t] = MFMA16(ah1, bh1, sacc[t]);
        sacc[t] = MFMA16(ah0, bl0, sacc[t]);
        sacc[t] = MFMA16(ah1, bl1, sacc[t]);
        sacc[t] = MFMA16(al0, bh0, sacc[t]);
        sacc[t] = MFMA16(al1, bh1, sacc[t]);
    }
    // scale + mask + rowsum (fp32-exact) + write Z into bufZ (ZSW)
    {
        float rsum[4] = {0.f, 0.f, 0.f, 0.f};
        float Mrv[4];
        #pragma unroll
        for (int reg = 0; reg < 4; ++reg) Mrv[reg] = Mr[16 * w + quad * 4 + reg];
        #pragma unroll
        for (int t = 0; t < 4; ++t){
            int c = 16 * t + ln;
            float cterm = colterm[c];
            #pragma unroll
            for (int reg = 0; reg < 4; ++reg){
                int r = 16 * w + quad * 4 + reg;
                float vS = (c <= r) ? sacc[t][reg] * SCALE * exp2f(cterm - Mrv[reg]) : 0.f;
                bufZ[ZSW(r, c)] = f2bf(vS);
                rsum[reg] += vS;
            }
        }
        #pragma unroll
        for (int off = 1; off < 16; off <<= 1){
            #pragma unroll
            for (int reg = 0; reg < 4; ++reg) rsum[reg] += __shfl_xor(rsum[reg], off);
        }
        if (ln == 0){
            #pragma unroll
            for (int reg = 0; reg < 4; ++reg) rowsum[16 * w + quad * 4 + reg] = rsum[reg];
        }
    }
    __syncthreads();   // #2: all k reads done; v^T staged

    // stage C ([v][k] natural order, split, SWZ vectorized writes) into bufA/bufB
    #pragma unroll
    for (int i = 0; i < 4; ++i){
        int idx = i * 1024 + tid * 4;
        int vrow = idx >> 6, k0 = idx & 63;
        float cv[4] = {Cr[i].x, Cr[i].y, Cr[i].z, Cr[i].w};
        ushort4v ch4, cl4;
        #pragma unroll
        for (int j = 0; j < 4; ++j){
            ushort_t h, l;
            split_bf(cv[j], h, l); ch4[j] = h; cl4[j] = l;
        }
        *(ushort4v*)&bufA[SWZ(vrow, k0)] = ch4;
        *(ushort4v*)&bufB[SWZ(vrow, k0)] = cl4;
    }
    __syncthreads();   // #3: C staged

    // ---- acc = (q @ C) * rowfac ----
    f32x4 acc[4];
    #pragma unroll
    for (int t = 0; t < 4; ++t){
        acc[t] = (f32x4){0.f, 0.f, 0.f, 0.f};
        short8 bh0 = *(const short8*)&bufA[SWZ(16 * t + ln, q8)];
        short8 bh1 = *(const short8*)&bufA[SWZ(16 * t + ln, 32 + q8)];
        short8 bl0 = *(const short8*)&bufB[SWZ(16 * t + ln, q8)];
        short8 bl1 = *(const short8*)&bufB[SWZ(16 * t + ln, 32 + q8)];
        acc[t] = MFMA16(ah0, bh0, acc[t]);
        acc[t] = MFMA16(ah1, bh1, acc[t]);
        acc[t] = MFMA16(ah0, bl0, acc[t]);
        acc[t] = MFMA16(ah1, bl1, acc[t]);
        acc[t] = MFMA16(al0, bh0, acc[t]);
        acc[t] = MFMA16(al1, bh1, acc[t]);
    }
    float rf[4], inv[4];
    #pragma unroll
    for (int reg = 0; reg < 4; ++reg){
        int r = 16 * w + quad * 4 + reg;
        rf[reg] = rowfac[r];
        float dn = fabsf(rf[reg] * qn[r] + rowsum[r]);
        inv[reg] = 1.f / fmaxf(dn, dncl[r]);
    }
    #pragma unroll
    for (int t = 0; t < 4; ++t){
        #pragma unroll
        for (int reg = 0; reg < 4; ++reg) acc[t][reg] *= rf[reg];
    }
    // ---- += S @ v ----
    short8 az0 = *(const short8*)&bufZ[ZSW(mrow, q8)];
    short8 az1 = *(const short8*)&bufZ[ZSW(mrow, 32 + q8)];
    #pragma unroll
    for (int t = 0; t < 4; ++t){
        short8 bh0 = *(const short8*)&bufV[SWZ(16 * t + ln, q8)];
        short8 bh1 = *(const short8*)&bufV[SWZ(16 * t + ln, 32 + q8)];
        acc[t] = MFMA16(az0, bh0, acc[t]);
        acc[t] = MFMA16(az1, bh1, acc[t]);
    }
    // epilogue
    #pragma unroll
    for (int t = 0; t < 4; ++t){
        int c = 16 * t + ln;
        #pragma unroll
        for (int reg = 0; reg < 4; ++reg){
            int r = 16 * w + quad * 4 + reg;
            out[(rowbase + r) * DV + c] = acc[t][reg] * inv[reg];
        }
    }
}

// ---------------- Fallback: fused sequential fp32 (no workspace) ----------------
__global__ __launch_bounds__(256) void fused_kernel(
    const float* __restrict__ qg, const float* __restrict__ kg, const float* __restrict__ vg,
    const float* __restrict__ ig, const float* __restrict__ fg,
    float* __restrict__ out, int T, int NT)
{
    const int s = blockIdx.x;
    const int tid = threadIdx.x;
    const int lane = tid & 63;

    __shared__ float X[BT][DK + 1];
    __shared__ float Y[BT][DK + 1];
    __shared__ float Cb[DK][DV];
    __shared__ __hip_bfloat16 Zh[BT][BT];
    __shared__ float colterm[BT], Mr[BT], rowfac[BT], dncl[BT], gscale[BT];
    __shared__ float nsh[DK], qn[BT], rowsum[BT], denom[BT];
    __shared__ float sh_dec;

    const float* qseq = qg + (size_t)s * T * DK;
    const float* kseq = kg + (size_t)s * T * DK;
    const float* vseq = vg + (size_t)s * T * DV;
    const float* iseq = ig + (size_t)s * T;
    const float* fseq = fg + (size_t)s * T;

    for (int idx = tid; idx < DK * DV; idx += 256) Cb[idx >> 6][idx & 63] = 0.f;
    if (tid < 64) nsh[lane] = 0.f;
    float m = 0.f;
    __syncthreads();

    const int r0 = (tid >> 4) * 4;
    const int c0 = (tid & 15) * 4;
    const int v0 = c0;

    for (int t = 0; t < NT; ++t){
        const size_t rb = (size_t)t * BT;
        if (tid < 64){
            float b = logsig_log2e(fseq[rb + lane]);
            #pragma unroll
            for (int off = 1; off < 64; off <<= 1){
                float y = __shfl_up(b, off);
                if (lane >= off) b += y;
            }
            float f_last = __shfl(b, 63);
            float a = iseq[rb + lane] * LOG2E_F - b;
            float p = a;
            #pragma unroll
            for (int off = 1; off < 64; off <<= 1){
                float y = __shfl_up(p, off);
                if (lane >= off) p = fmaxf(p, y);
            }
            float M = fmaxf(m, p);
            colterm[lane] = a;
            Mr[lane] = M;
            rowfac[lane] = SCALE * exp2f(m - M);
            dncl[lane] = exp2f(-(b + M));
            float g = a + f_last;
            float gm = g;
            #pragma unroll
            for (int off = 32; off > 0; off >>= 1) gm = fmaxf(gm, __shfl_xor(gm, off));
            float m_next = fmaxf(f_last + m, gm);
            gscale[lane] = exp2f(g - m_next);
            if (tid == 0) sh_dec = exp2f(f_last + m - m_next);
            m = m_next;
        }
        #pragma unroll
        for (int base = 0; base < BT * DK; base += 1024){
            int idx = base + tid * 4;
            int r = idx >> 6, c = idx & 63;
            float4 a4 = *(const float4*)(qseq + rb * DK + idx);
            X[r][c] = a4.x; X[r][c+1] = a4.y; X[r][c+2] = a4.z; X[r][c+3] = a4.w;
            float4 b4 = *(const float4*)(kseq + rb * DK + idx);
            Y[r][c] = b4.x; Y[r][c+1] = b4.y; Y[r][c+2] = b4.z; Y[r][c+3] = b4.w;
        }
        __syncthreads();

        float sacc[4][4] = {};
        for (int x = 0; x < DK; ++x){
            float xr[4], yc[4];
            #pragma unroll
            for (int j = 0; j < 4; ++j) xr[j] = X[r0 + j][x];
            #pragma unroll
            for (int j = 0; j < 4; ++j) yc[j] = Y[c0 + j][x];
            #pragma unroll
            for (int j = 0; j < 4; ++j)
                #pragma unroll
                for (int jj = 0; jj < 4; ++jj)
                    sacc[j][jj] = fmaf(xr[j], yc[jj], sacc[j][jj]);
        }
        float rs[4];
        #pragma unroll
        for (int j = 0; j < 4; ++j){
            int r = r0 + j;
            float Mrv = Mr[r];
            float acc = 0.f;
            #pragma unroll
            for (int jj = 0; jj < 4; ++jj){
                int c = c0 + jj;
                float vS = (c <= r) ? sacc[j][jj] * SCALE * exp2f(colterm[c] - Mrv) : 0.f;
                Zh[r][c] = __float2bfloat16(vS);
                acc += vS;
            }
            rs[j] = acc;
        }
        #pragma unroll
        for (int off = 1; off < 16; off <<= 1){
            #pragma unroll
            for (int j = 0; j < 4; ++j) rs[j] += __shfl_xor(rs[j], off);
        }
        if ((tid & 15) == 0){
            #pragma unroll
            for (int j = 0; j < 4; ++j) rowsum[r0 + j] = rs[j];
        }
        float acc1[4][4] = {};
        for (int x = 0; x < DK; ++x){
            float xr[4], yv[4];
            #pragma unroll
            for (int j = 0; j < 4; ++j) xr[j] = X[r0 + j][x];
            #pragma unroll
            for (int j = 0; j < 4; ++j) yv[j] = Cb[x][v0 + j];
            #pragma unroll
            for (int j = 0; j < 4; ++j)
                #pragma unroll
                for (int jj = 0; jj < 4; ++jj)
                    acc1[j][jj] = fmaf(xr[j], yv[jj], acc1[j][jj]);
        }
        if (tid < 64){
            float acc = 0.f;
            for (int x = 0; x < DK; ++x) acc = fmaf(X[lane][x], nsh[x], acc);
            qn[lane] = acc;
        }
        __syncthreads();

        #pragma unroll
        for (int base = 0; base < BT * DV; base += 1024){
            int idx = base + tid * 4;
            int r = idx >> 6, c = idx & 63;
            float4 a4 = *(const float4*)(vseq + rb * DV + idx);
            X[r][c] = a4.x; X[r][c+1] = a4.y; X[r][c+2] = a4.z; X[r][c+3] = a4.w;
        }
        if (tid < 64){
            float dn = fabsf(rowfac[lane] * qn[lane] + rowsum[lane]);
            denom[lane] = fmaxf(dn, dncl[lane]);
        }
        __syncthreads();

        float acc2[4][4] = {};
        for (int c = 0; c < BT; ++c){
            float zr[4], xv[4];
            #pragma unroll
            for (int j = 0; j < 4; ++j) zr[j] = __bfloat162float(Zh[r0 + j][c]);
            #pragma unroll
            for (int j = 0; j < 4; ++j) xv[j] = X[c][v0 + j];
            #pragma unroll
            for (int j = 0; j < 4; ++j)
                #pragma unroll
                for (int jj = 0; jj < 4; ++jj)
                    acc2[j][jj] = fmaf(zr[j], xv[jj], acc2[j][jj]);
        }
        #pragma unroll
        for (int j = 0; j < 4; ++j){
            int r = r0 + j;
            float rf = rowfac[r];
            float inv = 1.f / denom[r];
            float4 h4;
            h4.x = (acc1[j][0] * rf + acc2[j][0]) * inv;
            h4.y = (acc1[j][1] * rf + acc2[j][1]) * inv;
            h4.z = (acc1[j][2] * rf + acc2[j][2]) * inv;
            h4.w = (acc1[j][3] * rf + acc2[j][3]) * inv;
            *(float4*)(out + ((size_t)s * T + rb + r) * DV + v0) = h4;
        }
        {
            float dec = sh_dec;
            float cr[4][4];
            #pragma unroll
            for (int j = 0; j < 4; ++j)
                #pragma unroll
                for (int jj = 0; jj < 4; ++jj)
                    cr[j][jj] = Cb[r0 + j][c0 + jj] * dec;
            for (int c = 0; c < BT; ++c){
                float gs = gscale[c];
                float kd[4], xv[4];
                #pragma unroll
                for (int j = 0; j < 4; ++j) kd[j] = Y[c][r0 + j] * gs;
                #pragma unroll
                for (int jj = 0; jj < 4; ++jj) xv[jj] = X[c][c0 + jj];
                #pragma unroll
                for (int j = 0; j < 4; ++j)
                    #pragma unroll
                    for (int jj = 0; jj < 4; ++jj)
                        cr[j][jj] = fmaf(kd[j], xv[jj], cr[j][jj]);
            }
            #pragma unroll
            for (int j = 0; j < 4; ++j)
                #pragma unroll
                for (int jj = 0; jj < 4; ++jj)
                    Cb[r0 + j][c0 + jj] = cr[j][jj];
        }
        if (tid < 64){
            float acc = 0.f;
            for (int c = 0; c < BT; ++c) acc = fmaf(Y[c][lane], gscale[c], acc);
            nsh[lane] = nsh[lane] * sh_dec + acc;
        }
        __syncthreads();
    }
}

extern "C" void kernel_launch(void* const* d_in, const int* in_sizes, int n_in,
                              void* d_out, int out_size, void* d_ws, size_t ws_size,
                              hipStream_t stream)
{
    const float* q  = (const float*)d_in[0];
    const float* k  = (const float*)d_in[1];
    const float* v  = (const float*)d_in[2];
    const float* ii = (const float*)d_in[3];
    const float* ff = (const float*)d_in[4];
    float* out = (float*)d_out;

    const int T  = 4096;
    const int BH = in_sizes[3] / T;
    const int NT = T / BT;

    const size_t szC  = (size_t)BH * NT * DK * DV * sizeof(float);
    const size_t szA  = szC;
    const size_t szn  = (size_t)BH * NT * DK * sizeof(float);
    const size_t szs  = (size_t)BH * NT * sizeof(float);

    const size_t need_new = szA + szC + 2 * szn + 3 * szs;

    if (ws_size >= need_new){
        char* p = (char*)d_ws;
        float* A_ws    = (float*)p;            p += szA;
        float* Cws     = (float*)p;            p += szC;
        float* nloc_ws = (float*)p;            p += szn;
        float* nws     = (float*)p;            p += szn;
        float* fl_ws   = (float*)p;            p += szs;
        float* mloc_ws = (float*)p;            p += szs;
        float* mws     = (float*)p;
        stageA_kernel<<<dim3(NT, BH), 256, 0, stream>>>(k, v, ii, ff, A_ws, nloc_ws, fl_ws, mloc_ws, T, NT);
        stageB_kernel<<<dim3(16, BH), 256, 0, stream>>>(A_ws, nloc_ws, fl_ws, mloc_ws, Cws, nws, mws, NT);
        pass2_kernel<<<dim3(NT, BH), 256, 0, stream>>>(q, k, v, ii, ff, Cws, nws, mws, out, T, NT);
    } else {
        fused_kernel<<<dim3(BH), 256, 0, stream>>>(q, k, v, ii, ff, out, T, NT);
    }
}